// Round 5
// baseline (110.989 us; speedup 1.0000x reference)
//
#include <hip/hip_runtime.h>
#include <math.h>

// Shapes: x:(64,196,768) f32, ln_w/ln_b:(768,), sw/sb:(196,2,196), dw:(196,2)
// Algebra:
//   W[o,n]   = dw[o,0]*sw[o,0,n] + dw[o,1]*sw[o,1,n]
//   c[o]     = dw[o,0]*sum_n sb[o,0,n] + dw[o,1]*sum_n sb[o,1,n]
//   rowsum[o]= sum_n W[o,n]
//   xh[b,n,d]= (x[b,n,d]-mu[b,n])*rstd[b,n]
//   t[b,o,d] = ln_w[d]*sum_n W[o,n]*xh[b,n,d] + ln_b[d]*rowsum[o] + c[o]
//   out[b,o,d] = x[b,o,d] * (gelu_erf(t) + 1)
// GEMM via bf16 split-precision MFMA: W = Whi+Wlo, xh = Bhi+Blo,
//   acc += Whi*Bhi + Whi*Blo + Wlo*Bhi   (lo*lo dropped, ~1e-5 rel err)

#define B_   64
#define N_   196
#define D_   768
#define KPAD 224   // 7*32, zero-padded K
#define OPAD 256   // 2*128, zero-padded M

typedef __attribute__((ext_vector_type(8))) short bf16x8;
typedef __attribute__((ext_vector_type(4))) float f32x4;

__device__ __forceinline__ unsigned short bf16_rne(float f) {
    unsigned u = __builtin_bit_cast(unsigned, f);
    u += 0x7FFFu + ((u >> 16) & 1u);
    return (unsigned short)(u >> 16);
}
__device__ __forceinline__ float bf16_to_f(unsigned short h) {
    unsigned u = ((unsigned)h) << 16;
    return __builtin_bit_cast(float, u);
}

// ws layout (bytes):
//   mu     [B_*N_] f32      @ 0
//   rstd   [B_*N_] f32
//   rowsum [OPAD]  f32
//   cvec   [OPAD]  f32
//   Whi    [OPAD][KPAD] bf16(u16)
//   Wlo    [OPAD][KPAD] bf16(u16)

__global__ void prep_w_kernel(const float* __restrict__ sw,
                              const float* __restrict__ sb,
                              const float* __restrict__ dw,
                              unsigned short* __restrict__ Whi,
                              unsigned short* __restrict__ Wlo,
                              float* __restrict__ rowsum,
                              float* __restrict__ cvec) {
    int o = blockIdx.x;   // 0..255 (>=196 zero pad rows)
    int t = threadIdx.x;  // 0..255
    float w0 = 0.f, w1 = 0.f;
    if (o < N_) { w0 = dw[o * 2 + 0]; w1 = dw[o * 2 + 1]; }
    float val = 0.f, sbp = 0.f;
    if (o < N_ && t < N_) {
        val = w0 * sw[(o * 2 + 0) * N_ + t] + w1 * sw[(o * 2 + 1) * N_ + t];
        sbp = w0 * sb[(o * 2 + 0) * N_ + t] + w1 * sb[(o * 2 + 1) * N_ + t];
    }
    if (t < KPAD) {
        unsigned short h = bf16_rne(val);
        float lo = val - bf16_to_f(h);
        Whi[o * KPAD + t] = h;
        Wlo[o * KPAD + t] = bf16_rne(lo);
    }
    __shared__ float r1[256], r2[256];
    r1[t] = val; r2[t] = sbp;
    __syncthreads();
    for (int s = 128; s > 0; s >>= 1) {
        if (t < s) { r1[t] += r1[t + s]; r2[t] += r2[t + s]; }
        __syncthreads();
    }
    if (t == 0) { rowsum[o] = r1[0]; cvec[o] = r2[0]; }
}

__global__ void ln_stats_kernel(const float* __restrict__ x,
                                float* __restrict__ mu,
                                float* __restrict__ rstd) {
    int wave = threadIdx.x >> 6;
    int lane = threadIdx.x & 63;
    int row  = blockIdx.x * 4 + wave;
    const float4* xr = reinterpret_cast<const float4*>(x + (size_t)row * D_);
    float4 v0 = xr[lane];
    float4 v1 = xr[lane + 64];
    float4 v2 = xr[lane + 128];
    float s = v0.x + v0.y + v0.z + v0.w
            + v1.x + v1.y + v1.z + v1.w
            + v2.x + v2.y + v2.z + v2.w;
    #pragma unroll
    for (int off = 32; off >= 1; off >>= 1) s += __shfl_xor(s, off);
    float m = s * (1.0f / D_);
    float q = 0.f;
    {
        float d;
        d = v0.x - m; q += d * d;  d = v0.y - m; q += d * d;
        d = v0.z - m; q += d * d;  d = v0.w - m; q += d * d;
        d = v1.x - m; q += d * d;  d = v1.y - m; q += d * d;
        d = v1.z - m; q += d * d;  d = v1.w - m; q += d * d;
        d = v2.x - m; q += d * d;  d = v2.y - m; q += d * d;
        d = v2.z - m; q += d * d;  d = v2.w - m; q += d * d;
    }
    #pragma unroll
    for (int off = 32; off >= 1; off >>= 1) q += __shfl_xor(q, off);
    if (lane == 0) {
        mu[row]   = m;
        rstd[row] = rsqrtf(q * (1.0f / D_) + 1e-5f);
    }
}

// Block: 256 threads = 4 waves (wm = w>>1, wn = w&1).
// Block tile: 128 (o) x 64 (d). Wave tile: 64 (o) x 32 (d) = 4 x 2 frags of 16x16.
// K staged 32 at a time: xh normalized+split to bf16 hi/lo in LDS, k-innermost
// layout BsH/BsL[kq(4)][d(64)][k8(8)] so both write (b128, contiguous per wave)
// and read (b128 frag load) are conflict-free. A (W hi/lo) fragments are read
// directly from global (L1/L2-resident 225KB) - no LDS, no transpose.
__global__ __launch_bounds__(256) void gemm_mfma_kernel(
    const float* __restrict__ x,
    const float* __restrict__ ln_w,
    const float* __restrict__ ln_b,
    const unsigned short* __restrict__ Whi,
    const unsigned short* __restrict__ Wlo,
    const float* __restrict__ rowsum,
    const float* __restrict__ cvec,
    const float* __restrict__ mu,
    const float* __restrict__ rstd,
    float* __restrict__ out) {
    const int b  = blockIdx.y;
    const int mt = blockIdx.x & 1;    // o tile (2 x 128)
    const int dt = blockIdx.x >> 1;   // d tile (12 x 64)
    const int o0 = mt * 128, d0 = dt * 64;
    const int t = threadIdx.x;
    const int w = t >> 6, lane = t & 63;
    const int wm = w >> 1, wn = w & 1;
    const int m16 = lane & 15, g = lane >> 4;

    __shared__ __align__(16) unsigned short BsH[4 * 64 * 8];
    __shared__ __align__(16) unsigned short BsL[4 * 64 * 8];

    const float* xb  = x + (size_t)b * (N_ * D_);
    const float* mub = mu + b * N_;
    const float* rsb = rstd + b * N_;

    f32x4 acc[4][2];
    #pragma unroll
    for (int i = 0; i < 4; ++i)
        #pragma unroll
        for (int j = 0; j < 2; ++j)
            acc[i][j] = (f32x4){0.f, 0.f, 0.f, 0.f};

    const int sd = lane;      // staged d (0..63), coalesced across wave
    const int sk = w * 8;     // wave w stages k-octet w

    for (int k0 = 0; k0 < KPAD; k0 += 32) {
        // ---- global reads: x column-slab (8 k's of one d per thread) ----
        float xh[8];
        #pragma unroll
        for (int e = 0; e < 8; ++e) {
            int k = k0 + sk + e;
            float v = 0.f;
            if (k < N_)
                v = (xb[(size_t)k * D_ + d0 + sd] - mub[k]) * rsb[k];
            xh[e] = v;
        }
        // ---- A fragments straight from global (hi/lo) ----
        bf16x8 ah[4], al[4];
        #pragma unroll
        for (int mf = 0; mf < 4; ++mf) {
            int row = o0 + wm * 64 + mf * 16 + m16;
            ah[mf] = *reinterpret_cast<const bf16x8*>(Whi + (size_t)row * KPAD + k0 + g * 8);
            al[mf] = *reinterpret_cast<const bf16x8*>(Wlo + (size_t)row * KPAD + k0 + g * 8);
        }
        __syncthreads();   // prior iteration's B reads complete
        // ---- split to bf16 hi/lo, one b128 write each ----
        bf16x8 hv, lv;
        #pragma unroll
        for (int e = 0; e < 8; ++e) {
            unsigned short h = bf16_rne(xh[e]);
            hv[e] = (short)h;
            lv[e] = (short)bf16_rne(xh[e] - bf16_to_f(h));
        }
        *reinterpret_cast<bf16x8*>(&BsH[(w * 64 + sd) * 8]) = hv;
        *reinterpret_cast<bf16x8*>(&BsL[(w * 64 + sd) * 8]) = lv;
        __syncthreads();
        // ---- MFMA: 2 n-frags x 4 m-frags x 3 split products ----
        #pragma unroll
        for (int nf = 0; nf < 2; ++nf) {
            const int bidx = (g * 64 + wn * 32 + nf * 16 + m16) * 8;
            bf16x8 bh = *reinterpret_cast<const bf16x8*>(&BsH[bidx]);
            bf16x8 bl = *reinterpret_cast<const bf16x8*>(&BsL[bidx]);
            #pragma unroll
            for (int mf = 0; mf < 4; ++mf) {
                acc[mf][nf] = __builtin_amdgcn_mfma_f32_16x16x32_bf16(ah[mf], bh, acc[mf][nf], 0, 0, 0);
                acc[mf][nf] = __builtin_amdgcn_mfma_f32_16x16x32_bf16(ah[mf], bl, acc[mf][nf], 0, 0, 0);
                acc[mf][nf] = __builtin_amdgcn_mfma_f32_16x16x32_bf16(al[mf], bh, acc[mf][nf], 0, 0, 0);
            }
        }
    }

    // ---- epilogue: t = lnw*acc + lnb*rowsum + c; out = x*(gelu(t)+1) ----
    // D layout (verified): col = lane&15, row = (lane>>4)*4 + reg
    #pragma unroll
    for (int nf = 0; nf < 2; ++nf) {
        const int d = d0 + wn * 32 + nf * 16 + m16;
        const float lw = ln_w[d], lb = ln_b[d];
        #pragma unroll
        for (int mf = 0; mf < 4; ++mf) {
            #pragma unroll
            for (int r = 0; r < 4; ++r) {
                const int o = o0 + wm * 64 + mf * 16 + g * 4 + r;
                if (o < N_) {
                    float T = fmaf(lw, acc[mf][nf][r], fmaf(lb, rowsum[o], cvec[o]));
                    float gl = 0.5f * T * (1.0f + erff(T * 0.70710678118654752f));
                    out[((size_t)(b * N_ + o)) * D_ + d] = xb[(size_t)o * D_ + d] * (gl + 1.0f);
                }
            }
        }
    }
}

extern "C" void kernel_launch(void* const* d_in, const int* in_sizes, int n_in,
                              void* d_out, int out_size, void* d_ws, size_t ws_size,
                              hipStream_t stream) {
    const float* x    = (const float*)d_in[0];
    const float* ln_w = (const float*)d_in[1];
    const float* ln_b = (const float*)d_in[2];
    const float* sw   = (const float*)d_in[3];
    const float* sb   = (const float*)d_in[4];
    const float* dw   = (const float*)d_in[5];
    float* out = (float*)d_out;

    float* wsf = (float*)d_ws;
    float* mu     = wsf;                       // 12544
    float* rstd   = mu + B_ * N_;              // 12544
    float* rowsum = rstd + B_ * N_;            // 256
    float* cvec   = rowsum + OPAD;             // 256
    unsigned short* Whi = (unsigned short*)(cvec + OPAD);  // 256*224 u16
    unsigned short* Wlo = Whi + OPAD * KPAD;               // 256*224 u16

    prep_w_kernel<<<OPAD, 256, 0, stream>>>(sw, sb, dw, Whi, Wlo, rowsum, cvec);
    ln_stats_kernel<<<(B_ * N_) / 4, 256, 0, stream>>>(x, mu, rstd);
    gemm_mfma_kernel<<<dim3(24, B_), 256, 0, stream>>>(
        x, ln_w, ln_b, Whi, Wlo, rowsum, cvec, mu, rstd, out);
}

// Round 8
// 68.499 us; speedup vs baseline: 1.6203x; 1.6203x over previous
//
#include <hip/hip_runtime.h>
#include <math.h>

// Shapes: x:(64,196,768) f32, ln_w/ln_b:(768,), sw/sb:(196,2,196), dw:(196,2)
// Algebra:
//   W[o,n]   = dw[o,0]*sw[o,0,n] + dw[o,1]*sw[o,1,n]
//   c[o]     = dw[o,0]*sum_n sb[o,0,n] + dw[o,1]*sum_n sb[o,1,n]
//   rowsum[o]= sum_n W[o,n]
//   xh[b,n,d]= (x[b,n,d]-mu[b,n])*rstd[b,n]
//   t[b,o,d] = ln_w[d]*sum_n W[o,n]*xh[b,n,d] + ln_b[d]*rowsum[o] + c[o]
//   out[b,o,d] = x[b,o,d] * (gelu_erf(t) + 1)
// bf16 split MFMA: acc += Whi*Bhi + Whi*Blo + Wlo*Bhi (lo*lo dropped).
// R6 structure: FULL-K LDS staging (one bulk load phase, ONE barrier, then a
// pure MFMA phase) to fix the R5 latency-bound regime (MfmaUtil 5.7%,
// VALUBusy 19%: 14 barrier micro-phases exposed memory latency).

#define B_   64
#define N_   196
#define D_   768
#define KP   256   // padded K and padded O (32 k-octets)

typedef __attribute__((ext_vector_type(8))) short bf16x8;
typedef __attribute__((ext_vector_type(4))) float f32x4;

__device__ __forceinline__ unsigned short bf16_rne(float f) {
    unsigned u = __builtin_bit_cast(unsigned, f);
    u += 0x7FFFu + ((u >> 16) & 1u);
    return (unsigned short)(u >> 16);
}
__device__ __forceinline__ float bf16_to_f(unsigned short h) {
    unsigned u = ((unsigned)h) << 16;
    return __builtin_bit_cast(float, u);
}

__global__ void prep_w_kernel(const float* __restrict__ sw,
                              const float* __restrict__ sb,
                              const float* __restrict__ dw,
                              unsigned short* __restrict__ Whi,
                              unsigned short* __restrict__ Wlo,
                              float* __restrict__ rowsum,
                              float* __restrict__ cvec) {
    int o = blockIdx.x;   // 0..255 (>=196 zero pad rows)
    int t = threadIdx.x;  // 0..255 == KP-1
    float w0 = 0.f, w1 = 0.f;
    if (o < N_) { w0 = dw[o * 2 + 0]; w1 = dw[o * 2 + 1]; }
    float val = 0.f, sbp = 0.f;
    if (o < N_ && t < N_) {
        val = w0 * sw[(o * 2 + 0) * N_ + t] + w1 * sw[(o * 2 + 1) * N_ + t];
        sbp = w0 * sb[(o * 2 + 0) * N_ + t] + w1 * sb[(o * 2 + 1) * N_ + t];
    }
    unsigned short h = bf16_rne(val);
    Whi[o * KP + t] = h;
    Wlo[o * KP + t] = bf16_rne(val - bf16_to_f(h));
    __shared__ float r1[256], r2[256];
    r1[t] = val; r2[t] = sbp;
    __syncthreads();
    for (int s = 128; s > 0; s >>= 1) {
        if (t < s) { r1[t] += r1[t + s]; r2[t] += r2[t + s]; }
        __syncthreads();
    }
    if (t == 0) { rowsum[o] = r1[0]; cvec[o] = r2[0]; }
}

__global__ void ln_stats_kernel(const float* __restrict__ x,
                                float* __restrict__ mu,
                                float* __restrict__ rstd) {
    int wave = threadIdx.x >> 6;
    int lane = threadIdx.x & 63;
    int row  = blockIdx.x * 4 + wave;
    const float4* xr = reinterpret_cast<const float4*>(x + (size_t)row * D_);
    float4 v0 = xr[lane];
    float4 v1 = xr[lane + 64];
    float4 v2 = xr[lane + 128];
    float s = v0.x + v0.y + v0.z + v0.w
            + v1.x + v1.y + v1.z + v1.w
            + v2.x + v2.y + v2.z + v2.w;
    #pragma unroll
    for (int off = 32; off >= 1; off >>= 1) s += __shfl_xor(s, off);
    float m = s * (1.0f / D_);
    float q = 0.f;
    {
        float d;
        d = v0.x - m; q += d * d;  d = v0.y - m; q += d * d;
        d = v0.z - m; q += d * d;  d = v0.w - m; q += d * d;
        d = v1.x - m; q += d * d;  d = v1.y - m; q += d * d;
        d = v1.z - m; q += d * d;  d = v1.w - m; q += d * d;
        d = v2.x - m; q += d * d;  d = v2.y - m; q += d * d;
        d = v2.z - m; q += d * d;  d = v2.w - m; q += d * d;
    }
    #pragma unroll
    for (int off = 32; off >= 1; off >>= 1) q += __shfl_xor(q, off);
    if (lane == 0) {
        mu[row]   = m;
        rstd[row] = rsqrtf(q * (1.0f / D_) + 1e-5f);
    }
}

// Grid: (12 d-tiles, 64 b). Block: 512 threads = 8 waves.
// Wave w owns o-slice [w*32, w*32+32) (2 mf frags) x full 64 d (4 nf frags).
// LDS: BsH/BsL[32 koct][64 d][8 k] bf16 = 32 KB each; written ONCE (full K),
// one barrier, then 7 K-steps of pure {A-prefetch from L2, ds_read, MFMA}.
// Blocks partition x: each x element staged exactly once across the grid.
__global__ __launch_bounds__(512, 4) void gemm_mfma_kernel(
    const float* __restrict__ x,
    const float* __restrict__ ln_w,
    const float* __restrict__ ln_b,
    const unsigned short* __restrict__ Whi,
    const unsigned short* __restrict__ Wlo,
    const float* __restrict__ rowsum,
    const float* __restrict__ cvec,
    const float* __restrict__ mu,
    const float* __restrict__ rstd,
    float* __restrict__ out) {
    const int b  = blockIdx.y;
    const int d0 = blockIdx.x * 64;
    const int t = threadIdx.x;
    const int w = t >> 6, lane = t & 63;
    const int m16 = lane & 15, g = lane >> 4;

    __shared__ __align__(16) unsigned short BsH[32 * 64 * 8];
    __shared__ __align__(16) unsigned short BsL[32 * 64 * 8];

    const float* xb  = x + (size_t)b * (N_ * D_);
    const float* mub = mu + b * N_;
    const float* rsb = rstd + b * N_;

    // ---- bulk staging: 32 coalesced row-loads per thread, all in flight ----
    float xv[4][8];
    #pragma unroll
    for (int p = 0; p < 4; ++p) {
        const int koct = p * 8 + w;
        #pragma unroll
        for (int e = 0; e < 8; ++e) {
            const int k = koct * 8 + e;
            xv[p][e] = (k < N_) ? xb[(size_t)k * D_ + d0 + lane] : 0.f;
        }
    }
    #pragma unroll
    for (int p = 0; p < 4; ++p) {
        const int koct = p * 8 + w;
        bf16x8 hv, lv;
        #pragma unroll
        for (int e = 0; e < 8; ++e) {
            const int k = koct * 8 + e;
            float v = 0.f;
            if (k < N_) v = (xv[p][e] - mub[k]) * rsb[k];
            unsigned short h = bf16_rne(v);
            hv[e] = (short)h;
            lv[e] = (short)bf16_rne(v - bf16_to_f(h));
        }
        const int addr = (koct * 64 + lane) * 8;
        *reinterpret_cast<bf16x8*>(&BsH[addr]) = hv;
        *reinterpret_cast<bf16x8*>(&BsL[addr]) = lv;
    }
    __syncthreads();

    // ---- MFMA phase: 7 K-steps (K=224 live; kocts 28..31 are zero, skipped) ----
    f32x4 acc[2][4];
    #pragma unroll
    for (int i = 0; i < 2; ++i)
        #pragma unroll
        for (int j = 0; j < 4; ++j)
            acc[i][j] = (f32x4){0.f, 0.f, 0.f, 0.f};

    const int arow0 = (w * 32 + 0 * 16 + m16) * KP;
    const int arow1 = (w * 32 + 1 * 16 + m16) * KP;

    bf16x8 ah[2][2], al[2][2];
    ah[0][0] = *reinterpret_cast<const bf16x8*>(&Whi[arow0 + g * 8]);
    ah[0][1] = *reinterpret_cast<const bf16x8*>(&Whi[arow1 + g * 8]);
    al[0][0] = *reinterpret_cast<const bf16x8*>(&Wlo[arow0 + g * 8]);
    al[0][1] = *reinterpret_cast<const bf16x8*>(&Wlo[arow1 + g * 8]);

    #pragma unroll
    for (int kq = 0; kq < 7; ++kq) {
        const int cur = kq & 1, nxt = cur ^ 1;
        if (kq < 6) {
            const int col = (kq + 1) * 32 + g * 8;
            ah[nxt][0] = *reinterpret_cast<const bf16x8*>(&Whi[arow0 + col]);
            ah[nxt][1] = *reinterpret_cast<const bf16x8*>(&Whi[arow1 + col]);
            al[nxt][0] = *reinterpret_cast<const bf16x8*>(&Wlo[arow0 + col]);
            al[nxt][1] = *reinterpret_cast<const bf16x8*>(&Wlo[arow1 + col]);
        }
        #pragma unroll
        for (int nf = 0; nf < 4; ++nf) {
            const int baddr = ((kq * 4 + g) * 64 + nf * 16 + m16) * 8;
            bf16x8 bh = *reinterpret_cast<const bf16x8*>(&BsH[baddr]);
            bf16x8 bl = *reinterpret_cast<const bf16x8*>(&BsL[baddr]);
            #pragma unroll
            for (int mf = 0; mf < 2; ++mf) {
                acc[mf][nf] = __builtin_amdgcn_mfma_f32_16x16x32_bf16(ah[cur][mf], bh, acc[mf][nf], 0, 0, 0);
                acc[mf][nf] = __builtin_amdgcn_mfma_f32_16x16x32_bf16(ah[cur][mf], bl, acc[mf][nf], 0, 0, 0);
                acc[mf][nf] = __builtin_amdgcn_mfma_f32_16x16x32_bf16(al[cur][mf], bh, acc[mf][nf], 0, 0, 0);
            }
        }
    }

    // ---- epilogue: t = lnw*acc + lnb*rowsum + c; out = x*(gelu(t)+1) ----
    // C/D layout: col(d) = lane&15, row(o) = (lane>>4)*4 + reg
    float lwv[4], lbv[4];
    #pragma unroll
    for (int nf = 0; nf < 4; ++nf) {
        lwv[nf] = ln_w[d0 + nf * 16 + m16];
        lbv[nf] = ln_b[d0 + nf * 16 + m16];
    }
    #pragma unroll
    for (int mf = 0; mf < 2; ++mf) {
        #pragma unroll
        for (int r = 0; r < 4; ++r) {
            const int o = w * 32 + mf * 16 + g * 4 + r;
            if (o < N_) {
                const float rs = rowsum[o], cc = cvec[o];
                #pragma unroll
                for (int nf = 0; nf < 4; ++nf) {
                    const int d = d0 + nf * 16 + m16;
                    float T = fmaf(lwv[nf], acc[mf][nf][r], fmaf(lbv[nf], rs, cc));
                    float gl = 0.5f * T * (1.0f + erff(T * 0.70710678118654752f));
                    out[((size_t)(b * N_ + o)) * D_ + d] = xb[(size_t)o * D_ + d] * (gl + 1.0f);
                }
            }
        }
    }
}

extern "C" void kernel_launch(void* const* d_in, const int* in_sizes, int n_in,
                              void* d_out, int out_size, void* d_ws, size_t ws_size,
                              hipStream_t stream) {
    const float* x    = (const float*)d_in[0];
    const float* ln_w = (const float*)d_in[1];
    const float* ln_b = (const float*)d_in[2];
    const float* sw   = (const float*)d_in[3];
    const float* sb   = (const float*)d_in[4];
    const float* dw   = (const float*)d_in[5];
    float* out = (float*)d_out;

    float* wsf = (float*)d_ws;
    float* mu     = wsf;                       // 12544 f32
    float* rstd   = mu + B_ * N_;              // 12544 f32
    float* rowsum = rstd + B_ * N_;            // 256 f32
    float* cvec   = rowsum + KP;               // 256 f32
    unsigned short* Whi = (unsigned short*)(cvec + KP);    // 256*256 u16
    unsigned short* Wlo = Whi + KP * KP;                   // 256*256 u16

    prep_w_kernel<<<KP, 256, 0, stream>>>(sw, sb, dw, Whi, Wlo, rowsum, cvec);
    ln_stats_kernel<<<(B_ * N_) / 4, 256, 0, stream>>>(x, mu, rstd);
    gemm_mfma_kernel<<<dim3(12, B_), 512, 0, stream>>>(
        x, ln_w, ln_b, Whi, Wlo, rowsum, cvec, mu, rstd, out);
}